// Round 1
// baseline (668.674 us; speedup 1.0000x reference)
//
#include <hip/hip_runtime.h>
#include <math.h>

// BEV (4,128,512,512) f32 -> cylindrical (4,128,64,2048) f32.
// col[b,c,j] = bilinear(bev[b,c], fixed circle point j); out broadcasts col over H_C=64.
// Write-BW bound: 256 MiB out. One thread computes 4 j's, writes float4 x 64 rows.

namespace {
constexpr int BB = 4, CC = 128, HB = 512, WB = 512, HC = 64, WC = 2048;
constexpr float XMIN = -50.0f, XMAX = 50.0f, YMIN = -50.0f, YMAX = 50.0f;
constexpr float MAX_RANGE = 50.0f;

__device__ __forceinline__ float sample_col(const float* __restrict__ img, int j) {
    const float PI = 3.14159265358979323846f;
    float phi = -PI + (float)j * (2.0f * PI / (float)(WC - 1));
    float xg = MAX_RANGE * cosf(phi);
    float yg = MAX_RANGE * sinf(phi);
    float x = (xg - XMIN) * ((float)(WB - 1) / (XMAX - XMIN));
    float y = (YMAX - yg) * ((float)(HB - 1) / (YMAX - YMIN));
    float fx0 = floorf(x), fy0 = floorf(y);
    int x0 = (int)fx0, y0 = (int)fy0;
    int x1 = x0 + 1, y1 = y0 + 1;
    float wx1 = x - fx0, wx0 = 1.0f - wx1;
    float wy1 = y - fy0, wy0 = 1.0f - wy1;

    float acc = 0.0f;
    {   // (x0, y0)
        bool v = (x0 >= 0) & (x0 < WB) & (y0 >= 0) & (y0 < HB);
        int xc = min(max(x0, 0), WB - 1), yc = min(max(y0, 0), HB - 1);
        acc += img[yc * WB + xc] * (v ? wx0 * wy0 : 0.0f);
    }
    {   // (x1, y0)
        bool v = (x1 >= 0) & (x1 < WB) & (y0 >= 0) & (y0 < HB);
        int xc = min(max(x1, 0), WB - 1), yc = min(max(y0, 0), HB - 1);
        acc += img[yc * WB + xc] * (v ? wx1 * wy0 : 0.0f);
    }
    {   // (x0, y1)
        bool v = (x0 >= 0) & (x0 < WB) & (y1 >= 0) & (y1 < HB);
        int xc = min(max(x0, 0), WB - 1), yc = min(max(y1, 0), HB - 1);
        acc += img[yc * WB + xc] * (v ? wx0 * wy1 : 0.0f);
    }
    {   // (x1, y1)
        bool v = (x1 >= 0) & (x1 < WB) & (y1 >= 0) & (y1 < HB);
        int xc = min(max(x1, 0), WB - 1), yc = min(max(y1, 0), HB - 1);
        acc += img[yc * WB + xc] * (v ? wx1 * wy1 : 0.0f);
    }
    return acc;
}
} // namespace

__global__ __launch_bounds__(256) void bev2cyl_kernel(const float* __restrict__ bev,
                                                      float* __restrict__ out) {
    // total threads = B*C*WC/4 = 262144; 512 threads per (b,c) image
    int t = blockIdx.x * 256 + threadIdx.x;
    int bc = t >> 9;          // t / 512
    int jq = t & 511;         // quad index within the 2048 j's
    int j0 = jq << 2;

    const float* img = bev + (size_t)bc * (size_t)(HB * WB);

    float4 v;
    v.x = sample_col(img, j0 + 0);
    v.y = sample_col(img, j0 + 1);
    v.z = sample_col(img, j0 + 2);
    v.w = sample_col(img, j0 + 3);

    float* o = out + (size_t)bc * (size_t)(HC * WC) + j0;
#pragma unroll 8
    for (int h = 0; h < HC; ++h) {
        *(float4*)o = v;
        o += WC;
    }
}

extern "C" void kernel_launch(void* const* d_in, const int* in_sizes, int n_in,
                              void* d_out, int out_size, void* d_ws, size_t ws_size,
                              hipStream_t stream) {
    const float* bev = (const float*)d_in[0];
    float* out = (float*)d_out;
    // B*C*WC/4 threads / 256 per block = 1024 blocks
    dim3 grid(BB * CC * WC / 4 / 256);
    dim3 block(256);
    bev2cyl_kernel<<<grid, block, 0, stream>>>(bev, out);
}

// Round 2
// 664.804 us; speedup vs baseline: 1.0058x; 1.0058x over previous
//
#include <hip/hip_runtime.h>
#include <math.h>

// BEV (4,128,512,512) f32 -> cylindrical (4,128,64,2048) f32.
// Two-phase: (1) compute col[b,c,j] = bilinear sample of bev[b,c] at circle
// point j into d_ws (4 MiB); (2) pure streaming broadcast of col over H_C=64
// rows -> 256 MiB sequential writes (fill-kernel shaped, targets ~6.4 TB/s).

namespace {
constexpr int BB = 4, CC = 128, HB = 512, WB = 512, HC = 64, WC = 2048;
constexpr float XMIN = -50.0f, XMAX = 50.0f, YMIN = -50.0f, YMAX = 50.0f;
constexpr float MAX_RANGE = 50.0f;

__device__ __forceinline__ float sample_col(const float* __restrict__ img, int j) {
    const float PI = 3.14159265358979323846f;
    float phi = -PI + (float)j * (2.0f * PI / (float)(WC - 1));
    float xg = MAX_RANGE * cosf(phi);
    float yg = MAX_RANGE * sinf(phi);
    float x = (xg - XMIN) * ((float)(WB - 1) / (XMAX - XMIN));
    float y = (YMAX - yg) * ((float)(HB - 1) / (YMAX - YMIN));
    float fx0 = floorf(x), fy0 = floorf(y);
    int x0 = (int)fx0, y0 = (int)fy0;
    int x1 = x0 + 1, y1 = y0 + 1;
    float wx1 = x - fx0, wx0 = 1.0f - wx1;
    float wy1 = y - fy0, wy0 = 1.0f - wy1;

    float acc = 0.0f;
    {   // (x0, y0)
        bool v = (x0 >= 0) & (x0 < WB) & (y0 >= 0) & (y0 < HB);
        int xc = min(max(x0, 0), WB - 1), yc = min(max(y0, 0), HB - 1);
        acc += img[yc * WB + xc] * (v ? wx0 * wy0 : 0.0f);
    }
    {   // (x1, y0)
        bool v = (x1 >= 0) & (x1 < WB) & (y0 >= 0) & (y0 < HB);
        int xc = min(max(x1, 0), WB - 1), yc = min(max(y0, 0), HB - 1);
        acc += img[yc * WB + xc] * (v ? wx1 * wy0 : 0.0f);
    }
    {   // (x0, y1)
        bool v = (x0 >= 0) & (x0 < WB) & (y1 >= 0) & (y1 < HB);
        int xc = min(max(x0, 0), WB - 1), yc = min(max(y1, 0), HB - 1);
        acc += img[yc * WB + xc] * (v ? wx0 * wy1 : 0.0f);
    }
    {   // (x1, y1)
        bool v = (x1 >= 0) & (x1 < WB) & (y1 >= 0) & (y1 < HB);
        int xc = min(max(x1, 0), WB - 1), yc = min(max(y1, 0), HB - 1);
        acc += img[yc * WB + xc] * (v ? wx1 * wy1 : 0.0f);
    }
    return acc;
}
} // namespace

// Phase 1: one thread per (b,c,j) -> col value. 1,048,576 threads.
__global__ __launch_bounds__(256) void col_kernel(const float* __restrict__ bev,
                                                  float* __restrict__ col) {
    int t = blockIdx.x * 256 + threadIdx.x;      // < B*C*WC
    int bc = t >> 11;                             // t / 2048
    int j  = t & (WC - 1);
    const float* img = bev + (size_t)bc * (size_t)(HB * WB);
    col[t] = sample_col(img, j);
}

// Phase 2: one float4 per thread, fully sequential writes. 16,777,216 threads.
__global__ __launch_bounds__(256) void bcast_kernel(const float* __restrict__ col,
                                                    float* __restrict__ out) {
    int t = blockIdx.x * 256 + threadIdx.x;      // < B*C*HC*WC/4
    int bc = t >> 15;                             // / (HC*WC/4 = 32768)
    int r  = t & 32767;                           // h*512 + jq
    int jq = r & 511;
    const float4* colv = (const float4*)col;
    float4 v = colv[(bc << 9) + jq];
    ((float4*)out)[t] = v;
}

extern "C" void kernel_launch(void* const* d_in, const int* in_sizes, int n_in,
                              void* d_out, int out_size, void* d_ws, size_t ws_size,
                              hipStream_t stream) {
    const float* bev = (const float*)d_in[0];
    float* out = (float*)d_out;
    float* col = (float*)d_ws;                    // 4 MiB of the workspace

    col_kernel<<<dim3(BB * CC * WC / 256), dim3(256), 0, stream>>>(bev, col);
    bcast_kernel<<<dim3(BB * CC * HC * WC / 4 / 256), dim3(256), 0, stream>>>(col, out);
}